// Round 1
// baseline (947.926 us; speedup 1.0000x reference)
//
#include <hip/hip_runtime.h>
#include <math.h>

#define BDIM 16
#define HSZ 64
#define NHEAD 16
#define DELTA 64

// pos_feat[j][d] = sum_e rel[j][e] * W_pos[d][e], (64,16)
__global__ void posfeat_kernel(const float* __restrict__ rel, const float* __restrict__ Wpos,
                               float* __restrict__ pf) {
    int tid = threadIdx.x;            // 1024 threads
    int j = tid >> 4, d = tid & 15;
    float acc = 0.f;
#pragma unroll
    for (int e = 0; e < 16; ++e) acc += rel[j * 16 + e] * Wpos[d * 16 + e];
    pf[j * 16 + d] = acc;
}

// C[M,N] = A[M,K] @ W[N,K]^T + bias[N]; M,N multiples of 64, K multiple of 16.
__global__ __launch_bounds__(256) void gemm_nt(const float* __restrict__ A,
                                               const float* __restrict__ W,
                                               const float* __restrict__ bias,
                                               float* __restrict__ C,
                                               int M, int N, int K) {
    __shared__ float As[16][64];   // [k][m]
    __shared__ float Bs[16][64];   // [k][n]
    int tid = threadIdx.x;
    int tx = tid & 15, ty = tid >> 4;
    int bm = blockIdx.y * 64, bn = blockIdx.x * 64;
    int r = tid >> 2, c = tid & 3;
    float acc[4][4] = {{0.f}};
    const float* Aptr = A + (long)(bm + r) * K + c * 4;
    const float* Wptr = W + (long)(bn + r) * K + c * 4;
    for (int kt = 0; kt < K; kt += 16) {
        float4 a4 = *(const float4*)(Aptr + kt);
        float4 b4 = *(const float4*)(Wptr + kt);
        __syncthreads();
        As[c * 4 + 0][r] = a4.x; As[c * 4 + 1][r] = a4.y;
        As[c * 4 + 2][r] = a4.z; As[c * 4 + 3][r] = a4.w;
        Bs[c * 4 + 0][r] = b4.x; Bs[c * 4 + 1][r] = b4.y;
        Bs[c * 4 + 2][r] = b4.z; Bs[c * 4 + 3][r] = b4.w;
        __syncthreads();
#pragma unroll
        for (int kk = 0; kk < 16; ++kk) {
            float4 av = *(const float4*)&As[kk][ty * 4];
            float4 bv = *(const float4*)&Bs[kk][tx * 4];
            float a[4] = {av.x, av.y, av.z, av.w};
            float b[4] = {bv.x, bv.y, bv.z, bv.w};
#pragma unroll
            for (int i = 0; i < 4; ++i)
#pragma unroll
                for (int jj = 0; jj < 4; ++jj)
                    acc[i][jj] += a[i] * b[jj];
        }
    }
    float4 bv4 = *(const float4*)&bias[bn + tx * 4];
    float bb[4] = {bv4.x, bv4.y, bv4.z, bv4.w};
#pragma unroll
    for (int i = 0; i < 4; ++i) {
        float4 o;
        o.x = acc[i][0] + bb[0]; o.y = acc[i][1] + bb[1];
        o.z = acc[i][2] + bb[2]; o.w = acc[i][3] + bb[3];
        *(float4*)&C[(long)(bm + ty * 4 + i) * N + bn + tx * 4] = o;
    }
}

// One wave per (b,h,t). lane = j for logits/softmax; lane = hs for output.
__global__ __launch_bounds__(256) void attn_kernel(
    const float* __restrict__ disp,   // (B,T,NH,BD)
    const float* __restrict__ val,    // (B,T,NH,HS)
    const float* __restrict__ pf,     // (64,16)
    const float* __restrict__ Wf,     // (32,16)
    const float* __restrict__ bf,     // (32,)
    const float* __restrict__ Wb,     // (16,)
    const float* __restrict__ bb_p,   // scalar
    const float* __restrict__ Wd,     // (16,)
    const float* __restrict__ bd_p,   // scalar
    float* __restrict__ y,            // (B,T,C)
    int T) {
    __shared__ float sWf[32][16];
    __shared__ float sPf[16][64];     // transposed: [d][j]
    __shared__ float sBf[32];
    __shared__ float sWb[16];
    __shared__ float sWd[16];
    int tid = threadIdx.x;
    for (int i = tid; i < 512; i += 256) sWf[i >> 4][i & 15] = Wf[i];
    for (int i = tid; i < 1024; i += 256) sPf[i & 15][i >> 4] = pf[i];
    if (tid < 32) sBf[tid] = bf[tid];
    if (tid < 16) { sWb[tid] = Wb[tid]; sWd[tid] = Wd[tid]; }
    __syncthreads();
    float b_bond = *bb_p, b_dmg = *bd_p;

    int wid = tid >> 6, lane = tid & 63;
    long u = (long)blockIdx.x * 4 + wid;   // b*NH*T + h*T + t (t fastest -> L1 reuse on val)
    int t = (int)(u % T);
    int bh = (int)(u / T);
    int b = bh / NHEAD, h = bh % NHEAD;

    int j = lane;
    int tsrc = t + j - (DELTA - 1);
    bool valid = tsrc >= 0;

    const float* dC = disp + ((long)(b * T + t) * NHEAD + h) * BDIM;
    float s[BDIM];
    if (valid) {
        const float* dN = disp + ((long)(b * T + tsrc) * NHEAD + h) * BDIM;
#pragma unroll
        for (int d = 0; d < BDIM; ++d) s[d] = dN[d] - dC[d];
    } else {
#pragma unroll
        for (int d = 0; d < BDIM; ++d) s[d] = 0.f;
    }

    float fb[16], fd[16];
#pragma unroll
    for (int k = 0; k < 16; ++k) {
        float accb = sBf[k], accd = sBf[16 + k];
#pragma unroll
        for (int d = 0; d < BDIM; ++d) {
            accb += s[d] * sWf[k][d];
            accd += s[d] * sWf[16 + k][d];
        }
        fb[k] = accb; fd[k] = accd;
    }
    float bl = b_bond, dm = b_dmg;
    const float kInvSqrt2 = 0.7071067811865476f;
#pragma unroll
    for (int d = 0; d < 16; ++d) {
        float zb = fb[d] + sPf[d][j];
        float gb = 0.5f * zb * (1.f + erff(zb * kInvSqrt2));
        bl += gb * sWb[d];
        float zd = fd[d];
        float gd = 0.5f * zd * (1.f + erff(zd * kInvSqrt2));
        dm += gd * sWd[d];
    }
    float damage = 1.f / (1.f + expf(-dm));
    float logit = bl - 10.f * damage;
    if (!valid) logit = -INFINITY;

    // wave softmax over 64 lanes
    float m = logit;
    for (int off = 32; off >= 1; off >>= 1) m = fmaxf(m, __shfl_xor(m, off));
    float e = expf(logit - m);
    float ssum = e;
    for (int off = 32; off >= 1; off >>= 1) ssum += __shfl_xor(ssum, off);
    float w = e / ssum;

    // out[hs=lane] = sum_j w_j * val[b, t+j-63, h, lane]
    int jmin = (t >= DELTA - 1) ? 0 : (DELTA - 1 - t);
    float out = 0.f;
    const float* vbase = val + ((long)(b * T) * NHEAD + h) * HSZ + lane;
    for (int jj = jmin; jj < DELTA; ++jj) {
        float wj = __shfl(w, jj);
        int ts = t + jj - (DELTA - 1);
        out += wj * vbase[(long)ts * NHEAD * HSZ];
    }
    y[(long)(b * T + t) * (NHEAD * HSZ) + h * HSZ + lane] = out;
}

extern "C" void kernel_launch(void* const* d_in, const int* in_sizes, int n_in,
                              void* d_out, int out_size, void* d_ws, size_t ws_size,
                              hipStream_t stream) {
    const float* x       = (const float*)d_in[0];
    const float* W_disp  = (const float*)d_in[1];
    const float* b_disp  = (const float*)d_in[2];
    const float* W_val   = (const float*)d_in[3];
    const float* b_val   = (const float*)d_in[4];
    const float* rel     = (const float*)d_in[5];
    const float* W_fused = (const float*)d_in[6];
    const float* b_fused = (const float*)d_in[7];
    const float* W_pos   = (const float*)d_in[8];
    const float* W_bond  = (const float*)d_in[9];
    const float* b_bond  = (const float*)d_in[10];
    const float* W_dmg   = (const float*)d_in[11];
    const float* b_dmg   = (const float*)d_in[12];
    const float* W_cproj = (const float*)d_in[13];
    const float* b_cproj = (const float*)d_in[14];
    float* out = (float*)d_out;
    float* ws  = (float*)d_ws;

    const int B = 2, T = 1024, C = 1024;
    float* disp = ws;                        // B*T*NH*BD  = 524288 floats
    float* val  = disp + (long)B * T * NHEAD * BDIM;   // B*T*C = 2097152
    float* y    = val + (long)B * T * C;     // 2097152
    float* pf   = y + (long)B * T * C;       // 1024

    posfeat_kernel<<<1, 1024, 0, stream>>>(rel, W_pos, pf);
    gemm_nt<<<dim3((NHEAD * BDIM) / 64, (B * T) / 64), dim3(256), 0, stream>>>(
        x, W_disp, b_disp, disp, B * T, NHEAD * BDIM, C);
    gemm_nt<<<dim3(C / 64, (B * T) / 64), dim3(256), 0, stream>>>(
        x, W_val, b_val, val, B * T, C, C);
    attn_kernel<<<dim3(B * NHEAD * T / 4), dim3(256), 0, stream>>>(
        disp, val, pf, W_fused, b_fused, W_bond, b_bond, W_dmg, b_dmg, y, T);
    gemm_nt<<<dim3(C / 64, (B * T) / 64), dim3(256), 0, stream>>>(
        y, W_cproj, b_cproj, out, B * T, C, C);
}

// Round 2
// 375.772 us; speedup vs baseline: 2.5226x; 2.5226x over previous
//
#include <hip/hip_runtime.h>
#include <math.h>

#define BDIM 16
#define HSZ 64
#define NHEAD 16
#define DELTA 64

// pos_feat[j][d] = sum_e rel[j][e] * W_pos[d][e], (64,16)
__global__ void posfeat_kernel(const float* __restrict__ rel, const float* __restrict__ Wpos,
                               float* __restrict__ pf) {
    int tid = threadIdx.x;            // 1024 threads
    int j = tid >> 4, d = tid & 15;
    float acc = 0.f;
#pragma unroll
    for (int e = 0; e < 16; ++e) acc += rel[j * 16 + e] * Wpos[d * 16 + e];
    pf[j * 16 + d] = acc;
}

// C[M,N] = A[M,K] @ W[N,K]^T + bias[N]; M,N multiples of 64, K multiple of 16.
__global__ __launch_bounds__(256) void gemm_nt(const float* __restrict__ A,
                                               const float* __restrict__ W,
                                               const float* __restrict__ bias,
                                               float* __restrict__ C,
                                               int M, int N, int K) {
    __shared__ float As[16][64];   // [k][m]
    __shared__ float Bs[16][64];   // [k][n]
    int tid = threadIdx.x;
    int tx = tid & 15, ty = tid >> 4;
    int bm = blockIdx.y * 64, bn = blockIdx.x * 64;
    int r = tid >> 2, c = tid & 3;
    float acc[4][4] = {{0.f}};
    const float* Aptr = A + (long)(bm + r) * K + c * 4;
    const float* Wptr = W + (long)(bn + r) * K + c * 4;
    for (int kt = 0; kt < K; kt += 16) {
        float4 a4 = *(const float4*)(Aptr + kt);
        float4 b4 = *(const float4*)(Wptr + kt);
        __syncthreads();
        As[c * 4 + 0][r] = a4.x; As[c * 4 + 1][r] = a4.y;
        As[c * 4 + 2][r] = a4.z; As[c * 4 + 3][r] = a4.w;
        Bs[c * 4 + 0][r] = b4.x; Bs[c * 4 + 1][r] = b4.y;
        Bs[c * 4 + 2][r] = b4.z; Bs[c * 4 + 3][r] = b4.w;
        __syncthreads();
#pragma unroll
        for (int kk = 0; kk < 16; ++kk) {
            float4 av = *(const float4*)&As[kk][ty * 4];
            float4 bv = *(const float4*)&Bs[kk][tx * 4];
            float a[4] = {av.x, av.y, av.z, av.w};
            float b[4] = {bv.x, bv.y, bv.z, bv.w};
#pragma unroll
            for (int i = 0; i < 4; ++i)
#pragma unroll
                for (int jj = 0; jj < 4; ++jj)
                    acc[i][jj] += a[i] * b[jj];
        }
    }
    float4 bv4 = *(const float4*)&bias[bn + tx * 4];
    float bb[4] = {bv4.x, bv4.y, bv4.z, bv4.w};
#pragma unroll
    for (int i = 0; i < 4; ++i) {
        float4 o;
        o.x = acc[i][0] + bb[0]; o.y = acc[i][1] + bb[1];
        o.z = acc[i][2] + bb[2]; o.w = acc[i][3] + bb[3];
        *(float4*)&C[(long)(bm + ty * 4 + i) * N + bn + tx * 4] = o;
    }
}

// tanh-form gelu; z values here are small (|z| < ~1) so it matches erf-gelu
// to ~1e-5, far below the 2.7e-2 output threshold.
__device__ __forceinline__ float gelu_t(float z) {
    float u = 0.7978845608028654f * z * (1.f + 0.044715f * z * z);
    float e = __expf(2.f * u);
    float th = 1.f - 2.f / (e + 1.f);
    return 0.5f * z * (1.f + th);
}

#define PROJ_LD 33
#define W_LD 68

// One block per (b, h, 64-t tile). 256 threads.
__global__ __launch_bounds__(256) void attn_kernel(
    const float* __restrict__ disp,   // (B,T,NH,BD)
    const float* __restrict__ val,    // (B,T,NH,HS)
    const float* __restrict__ pf,     // (64,16)
    const float* __restrict__ Wf,     // (32,16)
    const float* __restrict__ bf,     // (32,)
    const float* __restrict__ Wb,     // (16,)
    const float* __restrict__ bb_p,   // scalar
    const float* __restrict__ Wd,     // (16,)
    const float* __restrict__ bd_p,   // scalar
    float* __restrict__ y,            // (B,T,C)
    int B, int T) {
    // Persistent: diagonal weight store sW[r][t_local], r = t_local + j.
    __shared__ float sW[127 * W_LD];             // 34,544 B
    // Overlay: phases A/B -> proj[127][33] + disp[127][16] + Wf[512];
    //          phase  D  -> val window [127][64]
    __shared__ float ov[127 * 64];               // 32,512 B
    float* sProj = ov;                           // 127*33 = 4191
    float* sDisp = ov + 127 * PROJ_LD;           // 2032
    float* sWfL  = ov + 127 * PROJ_LD + 127 * 16; // 512
    float* sVal  = ov;

    int tid = threadIdx.x;
    int ntile = T / 64;
    int t0 = (blockIdx.x % ntile) * 64;
    int bh = blockIdx.x / ntile;
    int b = bh / NHEAD, h = bh % NHEAD;

    int wave = tid >> 6, lane = tid & 63;

    // ---- Phase A: zero sW, stage disp window, compute proj ----
    {
        float4 z4 = make_float4(0.f, 0.f, 0.f, 0.f);
        for (int i = tid; i < (127 * W_LD) / 4; i += 256) ((float4*)sW)[i] = z4;
        for (int i = tid; i < 512; i += 256) sWfL[i] = Wf[i];
        for (int i = tid; i < 127 * 16; i += 256) {
            int r = i >> 4, d = i & 15;
            int ts = t0 + r - 63;
            sDisp[i] = (ts >= 0) ? disp[((long)(b * T + ts) * NHEAD + h) * BDIM + d] : 0.f;
        }
    }
    __syncthreads();
    {
        for (int idx = tid; idx < 127 * 32; idx += 256) {
            int r = idx >> 5, k = idx & 31;
            float a = 0.f;
#pragma unroll
            for (int d = 0; d < 16; ++d) a += sDisp[r * 16 + d] * sWfL[k * 16 + d];
            sProj[r * PROJ_LD + k] = a;
        }
    }

    // lane-constant params (lane == j): pf row + biases + dot weights
    float pfr[16], pdr[16], wbr[16], wdr[16];
#pragma unroll
    for (int q = 0; q < 4; ++q) {
        float4 a = ((const float4*)pf)[lane * 4 + q];
        float4 b0 = ((const float4*)bf)[q];        // bf[0..15]
        float4 b1 = ((const float4*)bf)[4 + q];    // bf[16..31]
        float4 wb = ((const float4*)Wb)[q];
        float4 wd = ((const float4*)Wd)[q];
        pfr[q * 4 + 0] = a.x + b0.x; pfr[q * 4 + 1] = a.y + b0.y;
        pfr[q * 4 + 2] = a.z + b0.z; pfr[q * 4 + 3] = a.w + b0.w;
        pdr[q * 4 + 0] = b1.x; pdr[q * 4 + 1] = b1.y;
        pdr[q * 4 + 2] = b1.z; pdr[q * 4 + 3] = b1.w;
        wbr[q * 4 + 0] = wb.x; wbr[q * 4 + 1] = wb.y;
        wbr[q * 4 + 2] = wb.z; wbr[q * 4 + 3] = wb.w;
        wdr[q * 4 + 0] = wd.x; wdr[q * 4 + 1] = wd.y;
        wdr[q * 4 + 2] = wd.z; wdr[q * 4 + 3] = wd.w;
    }
    float bbond = *bb_p, bdmg = *bd_p;
    __syncthreads();

    // ---- Phase B: logits + softmax, wave per t-row, lane = j ----
    int wbase = wave * 16;
    for (int rr = 0; rr < 16; ++rr) {
        int tl = wbase + rr;
        int rs = tl + lane;        // source window row (= tl + j)
        int rc = tl + 63;          // center window row
        bool valid = (t0 + rs - 63) >= 0;
        float bl = bbond, dm = bdmg;
#pragma unroll
        for (int k = 0; k < 16; ++k) {
            float cb = sProj[rc * PROJ_LD + k];
            float cd = sProj[rc * PROJ_LD + 16 + k];
            float pb = sProj[rs * PROJ_LD + k];
            float pd = sProj[rs * PROJ_LD + 16 + k];
            bl += gelu_t(pb - cb + pfr[k]) * wbr[k];
            dm += gelu_t(pd - cd + pdr[k]) * wdr[k];
        }
        float damage = 1.f / (1.f + __expf(-dm));
        float logit = bl - 10.f * damage;
        if (!valid) logit = -1e30f;
        float mx = logit;
#pragma unroll
        for (int off = 32; off >= 1; off >>= 1) mx = fmaxf(mx, __shfl_xor(mx, off));
        float e = __expf(logit - mx);
        float ssum = e;
#pragma unroll
        for (int off = 32; off >= 1; off >>= 1) ssum += __shfl_xor(ssum, off);
        sW[rs * W_LD + tl] = e / ssum;
    }
    __syncthreads();

    // ---- stage val window (overwrites overlay) ----
    for (int i = tid; i < 127 * 16; i += 256) {   // i indexes float4 slots
        int r = i >> 4, cq = i & 15;
        int ts = t0 + r - 63;
        float4 v = make_float4(0.f, 0.f, 0.f, 0.f);
        if (ts >= 0)
            v = ((const float4*)(val + ((long)(b * T + ts) * NHEAD + h) * HSZ))[cq];
        ((float4*)sVal)[i] = v;
    }
    __syncthreads();

    // ---- Phase D: banded weighted sum out[t][hs] = sum_j w * val ----
    int tg = lane >> 4, hsg = lane & 15;
    int hs = hsg * 4;
    int tbase = wbase + tg * 4;
    float4 acc0 = make_float4(0, 0, 0, 0), acc1 = acc0, acc2 = acc0, acc3 = acc0;
    for (int r = wbase; r < wbase + 79; ++r) {
        float4 v = *(const float4*)&sVal[r * 64 + hs];
        float4 w4 = *(const float4*)&sW[r * W_LD + tbase];
        acc0.x += w4.x * v.x; acc0.y += w4.x * v.y; acc0.z += w4.x * v.z; acc0.w += w4.x * v.w;
        acc1.x += w4.y * v.x; acc1.y += w4.y * v.y; acc1.z += w4.y * v.z; acc1.w += w4.y * v.w;
        acc2.x += w4.z * v.x; acc2.y += w4.z * v.y; acc2.z += w4.z * v.z; acc2.w += w4.z * v.w;
        acc3.x += w4.w * v.x; acc3.y += w4.w * v.y; acc3.z += w4.w * v.z; acc3.w += w4.w * v.w;
    }
    float4 outs[4] = {acc0, acc1, acc2, acc3};
#pragma unroll
    for (int i = 0; i < 4; ++i) {
        int t_local = tbase + i;
        *(float4*)&y[(long)(b * T + t0 + t_local) * (NHEAD * HSZ) + h * HSZ + hs] = outs[i];
    }
}

extern "C" void kernel_launch(void* const* d_in, const int* in_sizes, int n_in,
                              void* d_out, int out_size, void* d_ws, size_t ws_size,
                              hipStream_t stream) {
    const float* x       = (const float*)d_in[0];
    const float* W_disp  = (const float*)d_in[1];
    const float* b_disp  = (const float*)d_in[2];
    const float* W_val   = (const float*)d_in[3];
    const float* b_val   = (const float*)d_in[4];
    const float* rel     = (const float*)d_in[5];
    const float* W_fused = (const float*)d_in[6];
    const float* b_fused = (const float*)d_in[7];
    const float* W_pos   = (const float*)d_in[8];
    const float* W_bond  = (const float*)d_in[9];
    const float* b_bond  = (const float*)d_in[10];
    const float* W_dmg   = (const float*)d_in[11];
    const float* b_dmg   = (const float*)d_in[12];
    const float* W_cproj = (const float*)d_in[13];
    const float* b_cproj = (const float*)d_in[14];
    float* out = (float*)d_out;
    float* ws  = (float*)d_ws;

    const int B = 2, T = 1024, C = 1024;
    float* disp = ws;                                  // B*T*NH*BD  = 524288 floats
    float* val  = disp + (long)B * T * NHEAD * BDIM;   // B*T*C = 2097152
    float* y    = val + (long)B * T * C;               // 2097152
    float* pf   = y + (long)B * T * C;                 // 1024

    posfeat_kernel<<<1, 1024, 0, stream>>>(rel, W_pos, pf);
    gemm_nt<<<dim3((NHEAD * BDIM) / 64, (B * T) / 64), dim3(256), 0, stream>>>(
        x, W_disp, b_disp, disp, B * T, NHEAD * BDIM, C);
    gemm_nt<<<dim3(C / 64, (B * T) / 64), dim3(256), 0, stream>>>(
        x, W_val, b_val, val, B * T, C, C);
    attn_kernel<<<dim3(B * NHEAD * (T / 64)), dim3(256), 0, stream>>>(
        disp, val, pf, W_fused, b_fused, W_bond, b_bond, W_dmg, b_dmg, y, B, T);
    gemm_nt<<<dim3(C / 64, (B * T) / 64), dim3(256), 0, stream>>>(
        y, W_cproj, b_cproj, out, B * T, C, C);
}

// Round 4
// 208.982 us; speedup vs baseline: 4.5359x; 1.7981x over previous
//
#include <hip/hip_runtime.h>

#define BDIM 16
#define HSZ 64
#define NHEAD 16
#define DELTA 64
#define LOG2E 1.4426950408889634f

typedef __bf16 bf16x8 __attribute__((ext_vector_type(8)));
typedef float f32x4 __attribute__((ext_vector_type(4)));
typedef unsigned short us8 __attribute__((ext_vector_type(8)));
typedef unsigned short us2 __attribute__((ext_vector_type(2)));
typedef unsigned int u32;

__device__ __forceinline__ unsigned short f2bf(float f) {
    u32 u = __float_as_uint(f);
    return (unsigned short)((u + 0x7fffu + ((u >> 16) & 1u)) >> 16);
}
__device__ __forceinline__ float bf2f(unsigned short s) {
    return __uint_as_float(((u32)s) << 16);
}

__device__ __forceinline__ void gload_lds16(const void* g, void* l) {
    __builtin_amdgcn_global_load_lds(
        (const __attribute__((address_space(1))) void*)g,
        (__attribute__((address_space(3))) void*)l, 16, 0, 0);
}

// float -> bf16 cast, 4 elements/thread
__global__ __launch_bounds__(256) void cast_bf16(const float* __restrict__ src,
                                                 unsigned short* __restrict__ dst, int n4) {
    int i = blockIdx.x * 256 + threadIdx.x;
    if (i < n4) {
        float4 f = ((const float4*)src)[i];
        ushort4 o;
        o.x = f2bf(f.x); o.y = f2bf(f.y); o.z = f2bf(f.z); o.w = f2bf(f.w);
        ((ushort4*)dst)[i] = o;
    }
}

// pos_feat[j][d] = sum_e rel[j][e] * W_pos[d][e], (64,16)
__global__ void posfeat_kernel(const float* __restrict__ rel, const float* __restrict__ Wpos,
                               float* __restrict__ pf) {
    int tid = threadIdx.x;
    int j = tid >> 4, d = tid & 15;
    float acc = 0.f;
#pragma unroll
    for (int e = 0; e < 16; ++e) acc += rel[j * 16 + e] * Wpos[d * 16 + e];
    pf[j * 16 + d] = acc;
}

// C[M,N] = A[M,K] @ Bw[N,K]^T + bias. A,Bw bf16; C fp32 or bf16 (obf).
// BM=BN=BK=64, 256 threads = 4 waves, wave quadrant 32x32 (2x2 MFMA 16x16x32).
// LDS fragment-ordered: group g = kstep*4 + rowblock, slot = lane (m=lane&15, q=lane>>4).
__global__ __launch_bounds__(256) void gemm_bf16(const unsigned short* __restrict__ A,
                                                 const unsigned short* __restrict__ Bw,
                                                 const float* __restrict__ bias,
                                                 float* __restrict__ C,
                                                 unsigned short* __restrict__ Cb,
                                                 int N, int K, int obf) {
    __shared__ __align__(16) unsigned short lA[8 * 512];
    __shared__ __align__(16) unsigned short lB[8 * 512];
    int tid = threadIdx.x;
    int w = tid >> 6, lane = tid & 63;
    int bm = blockIdx.y * 64, bn = blockIdx.x * 64;
    int wr = w & 1, wc = w >> 1;
    int m16 = lane & 15, q = lane >> 4;
    f32x4 acc[2][2];
#pragma unroll
    for (int i = 0; i < 2; ++i)
#pragma unroll
        for (int j = 0; j < 2; ++j) acc[i][j] = (f32x4){0.f, 0.f, 0.f, 0.f};

    for (int kt = 0; kt < K; kt += 64) {
#pragma unroll
        for (int u = 0; u < 2; ++u) {
            int g = 2 * w + u;
            int s = g >> 2, rb = g & 3;
            const unsigned short* ga = A + (long)(bm + rb * 16 + m16) * K + kt + s * 32 + q * 8;
            const unsigned short* gb = Bw + (long)(bn + rb * 16 + m16) * K + kt + s * 32 + q * 8;
            gload_lds16(ga, &lA[g * 512]);
            gload_lds16(gb, &lB[g * 512]);
        }
        __syncthreads();
#pragma unroll
        for (int s = 0; s < 2; ++s) {
            bf16x8 a0 = *(const bf16x8*)&lA[(s * 4 + wr * 2 + 0) * 512 + lane * 8];
            bf16x8 a1 = *(const bf16x8*)&lA[(s * 4 + wr * 2 + 1) * 512 + lane * 8];
            bf16x8 b0 = *(const bf16x8*)&lB[(s * 4 + wc * 2 + 0) * 512 + lane * 8];
            bf16x8 b1 = *(const bf16x8*)&lB[(s * 4 + wc * 2 + 1) * 512 + lane * 8];
            acc[0][0] = __builtin_amdgcn_mfma_f32_16x16x32_bf16(a0, b0, acc[0][0], 0, 0, 0);
            acc[0][1] = __builtin_amdgcn_mfma_f32_16x16x32_bf16(a0, b1, acc[0][1], 0, 0, 0);
            acc[1][0] = __builtin_amdgcn_mfma_f32_16x16x32_bf16(a1, b0, acc[1][0], 0, 0, 0);
            acc[1][1] = __builtin_amdgcn_mfma_f32_16x16x32_bf16(a1, b1, acc[1][1], 0, 0, 0);
        }
        __syncthreads();
    }
    int rowb = bm + wr * 32, colb = bn + wc * 32;
#pragma unroll
    for (int j = 0; j < 2; ++j) {
        float bv = bias[colb + j * 16 + m16];
#pragma unroll
        for (int i = 0; i < 2; ++i) {
#pragma unroll
            for (int e = 0; e < 4; ++e) {
                int row = rowb + i * 16 + q * 4 + e;
                float v = acc[i][j][e] + bv;
                long idx = (long)row * N + colb + j * 16 + m16;
                if (obf) Cb[idx] = f2bf(v); else C[idx] = v;
            }
        }
    }
}

// fast tanh-form gelu via exp2 (matches erf-gelu to ~3e-3 abs worst-case; logits tolerant)
__device__ __forceinline__ float gelu_fast(float z) {
    float z2 = z * z;
    float p = __builtin_fmaf(0.044715f, z2, 1.0f);
    float e = __builtin_exp2f(z * 2.3022085f * p);
    float r = __builtin_amdgcn_rcpf(e + 1.f);
    return z - z * r;      // z * sigmoid(2u)
}

#define PROJ_LD 33
#define W_LD 68

// One block per (b, h, 64-t tile). 256 threads.
__global__ __launch_bounds__(256) void attn_kernel(
    const float* __restrict__ disp,             // (B,T,NH,BD) fp32
    const unsigned short* __restrict__ valb,    // (B,T,NH,HS) bf16
    const float* __restrict__ pf,               // (64,16)
    const float* __restrict__ Wf,               // (32,16)
    const float* __restrict__ bfu,              // (32,)
    const float* __restrict__ Wb,               // (16,)
    const float* __restrict__ bb_p,             // scalar
    const float* __restrict__ Wd,               // (16,)
    const float* __restrict__ bd_p,             // scalar
    unsigned short* __restrict__ y,             // (B,T,C) bf16
    int T) {
    __shared__ __align__(16) unsigned short sW[8640];          // 127 x 68 bf16 diagonal
    __shared__ __align__(16) float ov[127 * PROJ_LD + 127 * 16 + 512 + 16];
    float* sProj = ov;
    float* sDisp = ov + 127 * PROJ_LD;
    float* sWfT  = sDisp + 127 * 16;            // transposed [d][k] 16x32
    unsigned short* sVal = (unsigned short*)ov; // phase D overlay: 127 x 64 bf16

    int tid = threadIdx.x;
    int ntile = T / 64;
    int t0 = (blockIdx.x % ntile) * 64;
    int bh = blockIdx.x / ntile;
    int b = bh / NHEAD, h = bh % NHEAD;
    int wave = tid >> 6, lane = tid & 63;

    // ---- Phase A: zero sW, stage Wf^T + disp window, compute proj ----
    {
        uint4 z4 = make_uint4(0, 0, 0, 0);
        for (int i = tid; i < 1080; i += 256) ((uint4*)sW)[i] = z4;
        for (int i = tid; i < 512; i += 256) sWfT[(i & 15) * 32 + (i >> 4)] = Wf[i];
        for (int i = tid; i < 127 * 4; i += 256) {
            int r = i >> 2, qq = i & 3;
            int ts = t0 + r - 63;
            float4 v = make_float4(0.f, 0.f, 0.f, 0.f);
            if (ts >= 0)
                v = ((const float4*)(disp + ((long)(b * T + ts) * NHEAD + h) * BDIM))[qq];
            *(float4*)&sDisp[r * 16 + qq * 4] = v;
        }
    }
    __syncthreads();
    for (int idx = tid; idx < 127 * 32; idx += 256) {
        int r = idx >> 5, k = idx & 31;
        float a = 0.f;
#pragma unroll
        for (int d = 0; d < 16; ++d) a += sDisp[r * 16 + d] * sWfT[d * 32 + k];
        sProj[r * PROJ_LD + k] = a;
    }

    // lane-constant params (lane == j)
    float pfr[16], pdr[16], wbr[16], wdr[16];
#pragma unroll
    for (int qq = 0; qq < 4; ++qq) {
        float4 a = ((const float4*)pf)[lane * 4 + qq];
        float4 b0 = ((const float4*)bfu)[qq];
        float4 b1 = ((const float4*)bfu)[4 + qq];
        float4 wb = ((const float4*)Wb)[qq];
        float4 wd = ((const float4*)Wd)[qq];
        pfr[qq * 4 + 0] = a.x + b0.x; pfr[qq * 4 + 1] = a.y + b0.y;
        pfr[qq * 4 + 2] = a.z + b0.z; pfr[qq * 4 + 3] = a.w + b0.w;
        pdr[qq * 4 + 0] = b1.x; pdr[qq * 4 + 1] = b1.y;
        pdr[qq * 4 + 2] = b1.z; pdr[qq * 4 + 3] = b1.w;
        wbr[qq * 4 + 0] = wb.x; wbr[qq * 4 + 1] = wb.y;
        wbr[qq * 4 + 2] = wb.z; wbr[qq * 4 + 3] = wb.w;
        wdr[qq * 4 + 0] = wd.x; wdr[qq * 4 + 1] = wd.y;
        wdr[qq * 4 + 2] = wd.z; wdr[qq * 4 + 3] = wd.w;
    }
    float bbond = *bb_p, bdmg = *bd_p;
    __syncthreads();

    // ---- Phase B: logits + softmax, wave per t-row, lane = j ----
    int wbase = wave * 16;
    for (int rr = 0; rr < 16; ++rr) {
        int tl = wbase + rr;
        int rs = tl + lane, rc = tl + 63;
        bool valid = (t0 + rs - 63) >= 0;
        float bl = bbond, dm = bdmg;
#pragma unroll
        for (int k = 0; k < 16; ++k) {
            float cb = sProj[rc * PROJ_LD + k];
            float cd = sProj[rc * PROJ_LD + 16 + k];
            float pb = sProj[rs * PROJ_LD + k];
            float pd = sProj[rs * PROJ_LD + 16 + k];
            bl = __builtin_fmaf(gelu_fast(pb - cb + pfr[k]), wbr[k], bl);
            dm = __builtin_fmaf(gelu_fast(pd - cd + pdr[k]), wdr[k], dm);
        }
        float damage = __builtin_amdgcn_rcpf(1.f + __builtin_exp2f(-dm * LOG2E));
        float logit = bl - 10.f * damage;
        if (!valid) logit = -1e30f;
        float mx = logit;
#pragma unroll
        for (int off = 32; off >= 1; off >>= 1) mx = fmaxf(mx, __shfl_xor(mx, off));
        float e = __builtin_exp2f((logit - mx) * LOG2E);
        float ssum = e;
#pragma unroll
        for (int off = 32; off >= 1; off >>= 1) ssum += __shfl_xor(ssum, off);
        sW[rs * W_LD + tl] = f2bf(e * __builtin_amdgcn_rcpf(ssum));
    }
    __syncthreads();

    // ---- stage val window as bf16 (overwrites overlay) ----
    for (int i = tid; i < 127 * 8; i += 256) {
        int r = i >> 3, c = i & 7;
        int ts = t0 + r - 63;
        us8 v = (us8)0;
        if (ts >= 0)
            v = *(const us8*)(valb + ((long)(b * T + ts) * NHEAD + h) * HSZ + c * 8);
        *(us8*)&sVal[r * 64 + c * 8] = v;
    }
    __syncthreads();

    // ---- Phase D: banded weighted sum; lane = (tg 0..7) x (hsg 0..7) ----
    int tg = lane >> 3, hsg = lane & 7;
    int tb = wbase + tg * 2;
    float acc0[8], acc1[8];
#pragma unroll
    for (int i = 0; i < 8; ++i) { acc0[i] = 0.f; acc1[i] = 0.f; }
    for (int r = wbase; r < wbase + 79; ++r) {
        us8 v8 = *(const us8*)&sVal[r * 64 + hsg * 8];
        us2 w2 = *(const us2*)&sW[r * W_LD + tb];
        float w0 = bf2f(w2.x), w1 = bf2f(w2.y);
#pragma unroll
        for (int i = 0; i < 8; ++i) {
            float vf = bf2f(v8[i]);
            acc0[i] = __builtin_fmaf(w0, vf, acc0[i]);
            acc1[i] = __builtin_fmaf(w1, vf, acc1[i]);
        }
    }
#pragma unroll
    for (int e = 0; e < 2; ++e) {
        float* ac = e ? acc1 : acc0;
        us8 o;
#pragma unroll
        for (int i = 0; i < 8; ++i) o[i] = f2bf(ac[i]);
        *(us8*)&y[(long)(b * T + t0 + tb + e) * (NHEAD * HSZ) + h * HSZ + hsg * 8] = o;
    }
}

extern "C" void kernel_launch(void* const* d_in, const int* in_sizes, int n_in,
                              void* d_out, int out_size, void* d_ws, size_t ws_size,
                              hipStream_t stream) {
    const float* x       = (const float*)d_in[0];
    const float* W_disp  = (const float*)d_in[1];
    const float* b_disp  = (const float*)d_in[2];
    const float* W_val   = (const float*)d_in[3];
    const float* b_val   = (const float*)d_in[4];
    const float* rel     = (const float*)d_in[5];
    const float* W_fused = (const float*)d_in[6];
    const float* b_fused = (const float*)d_in[7];
    const float* W_pos   = (const float*)d_in[8];
    const float* W_bond  = (const float*)d_in[9];
    const float* b_bond  = (const float*)d_in[10];
    const float* W_dmg   = (const float*)d_in[11];
    const float* b_dmg   = (const float*)d_in[12];
    const float* W_cproj = (const float*)d_in[13];
    const float* b_cproj = (const float*)d_in[14];
    float* out = (float*)d_out;
    float* ws  = (float*)d_ws;

    const int B = 2, T = 1024, C = 1024;
    // workspace layout (floats)
    float* disp = ws;                                    // 524288
    float* pf   = disp + 524288;                         // 1024
    unsigned short* x_bf  = (unsigned short*)(pf + 1024);        // 2097152 us (reused as y_bf)
    unsigned short* val_bf = x_bf + 2097152;                     // 2097152 us
    unsigned short* Wd_bf  = val_bf + 2097152;                   // 262144 us
    unsigned short* Wv_bf  = Wd_bf + 262144;                     // 1048576 us
    unsigned short* Wc_bf  = Wv_bf + 1048576;                    // 1048576 us
    unsigned short* y_bf   = x_bf;   // reuse after val GEMM

    cast_bf16<<<2048, 256, 0, stream>>>(x, x_bf, 524288);
    cast_bf16<<<256, 256, 0, stream>>>(W_disp, Wd_bf, 65536);
    cast_bf16<<<1024, 256, 0, stream>>>(W_val, Wv_bf, 262144);
    cast_bf16<<<1024, 256, 0, stream>>>(W_cproj, Wc_bf, 262144);
    posfeat_kernel<<<1, 1024, 0, stream>>>(rel, W_pos, pf);

    // disp = x @ W_disp^T + b_disp  (fp32 out)
    gemm_bf16<<<dim3(4, 32), 256, 0, stream>>>(x_bf, Wd_bf, b_disp, disp, nullptr,
                                               NHEAD * BDIM, C, 0);
    // val = x @ W_val^T + b_val  (bf16 out)
    gemm_bf16<<<dim3(16, 32), 256, 0, stream>>>(x_bf, Wv_bf, b_val, nullptr, val_bf,
                                                C, C, 1);
    attn_kernel<<<dim3(B * NHEAD * (T / 64)), 256, 0, stream>>>(
        disp, val_bf, pf, W_fused, b_fused, W_bond, b_bond, W_dmg, b_dmg, y_bf, T);
    // out = y @ W_cproj^T + b_cproj  (fp32 out)
    gemm_bf16<<<dim3(16, 32), 256, 0, stream>>>(y_bf, Wc_bf, b_cproj, out, nullptr,
                                                C, C, 0);
}